// Round 4
// baseline (147.064 us; speedup 1.0000x reference)
//
#include <hip/hip_runtime.h>

#define KCODES 512
#define DDIM 64

typedef __attribute__((ext_vector_type(8))) short bf16x8;
typedef __attribute__((ext_vector_type(4))) float f32x4;

// ---- workspace layout (bytes) ----
#define WS_IMG    0          // 8 passes x 16384 B  (ehi 8KB swizzled | elo 8KB swizzled)
#define WS_ESQB   131072     // f32[512]  fl(esq + 0.5)   (biased, for screening keys)
#define WS_ESQ    133120     // f32[512]  raw np-pairwise esq (for bit-exact rescore)
#define WS_MAXE   135168     // f32       max|e|
#define WS_NEEDED 135172

__device__ __forceinline__ unsigned umin_(unsigned a, unsigned b) { return a < b ? a : b; }
__device__ __forceinline__ unsigned umax_(unsigned a, unsigned b) { return a > b ? a : b; }

// Split f32 into bf16 hi + bf16 lo (RNE).
__device__ __forceinline__ void bf16_split(float v, unsigned short& hi, unsigned short& lo) {
    unsigned u = __float_as_uint(v);
    unsigned r = u + 0x7fffu + ((u >> 16) & 1u);
    hi = (unsigned short)(r >> 16);
    float hf = __uint_as_float(((unsigned)hi) << 16);
    float l = v - hf;
    unsigned u2 = __float_as_uint(l);
    unsigned r2 = u2 + 0x7fffu + ((u2 >> 16) & 1u);
    lo = (unsigned short)(r2 >> 16);
}

// Bit-exact emulation of the numpy-f32 reference distance (verified rounds 2/3):
//   z_sq: sequential ascending-d, pre-rounded squares; cross: sequential, mul+add no fma
//   dist = fl( fl(z_sq - fl(2*cross)) + esq )
__device__ __forceinline__ float np_dist_strided(const float* __restrict__ zp,
                                                 const float* __restrict__ e, float esqk) {
    float zq = 0.f, cr = 0.f;
    #pragma unroll 8
    for (int d = 0; d < DDIM; ++d) {
        float zv = zp[(size_t)d * 4096];
        zq = __fadd_rn(zq, __fmul_rn(zv, zv));
        cr = __fadd_rn(cr, __fmul_rn(zv, e[d]));
    }
    return __fadd_rn(__fsub_rn(zq, __fmul_rn(2.0f, cr)), esqk);
}

// ---------------- pre-kernel: build split image + esq tables into ws ----------------
__global__ __launch_bounds__(512) void vq_pre_kernel(const float* __restrict__ emb,
                                                     char* __restrict__ ws)
{
    __shared__ float wmax[8];
    const int k = threadIdx.x;           // code 0..511
    const float* e = emb + k * DDIM;

    // esq np-pairwise (contiguous-axis reduce: 8-accumulator pattern, verified round 2)
    float r[8];
    #pragma unroll
    for (int j = 0; j < 8; ++j) r[j] = __fmul_rn(e[j], e[j]);
    #pragma unroll
    for (int i = 8; i < DDIM; i += 8)
        #pragma unroll
        for (int j = 0; j < 8; ++j)
            r[j] = __fadd_rn(r[j], __fmul_rn(e[i + j], e[i + j]));
    float esq = __fadd_rn(
        __fadd_rn(__fadd_rn(r[0], r[1]), __fadd_rn(r[2], r[3])),
        __fadd_rn(__fadd_rn(r[4], r[5]), __fadd_rn(r[6], r[7])));
    ((float*)(ws + WS_ESQ))[k]  = esq;
    ((float*)(ws + WS_ESQB))[k] = __fadd_rn(esq, 0.5f);

    // bf16 hi/lo split image, pre-swizzled to the LDS layout the main kernel reads
    const int pass = k >> 6, rr = k & 63;
    unsigned short* ehi = (unsigned short*)(ws + WS_IMG + pass * 16384);
    unsigned short* elo = (unsigned short*)(ws + WS_IMG + pass * 16384 + 8192);
    float me = 0.f;
    #pragma unroll
    for (int jidx = 0; jidx < 8; ++jidx) {
        bf16x8 hh, ll;
        #pragma unroll
        for (int j = 0; j < 8; ++j) {
            float v = e[jidx * 8 + j];
            me = fmaxf(me, fabsf(v));
            unsigned short h, l;
            bf16_split(v, h, l);
            hh[j] = (short)h; ll[j] = (short)l;
        }
        int off = rr * 64 + ((jidx ^ (rr & 7)) << 3);
        *(bf16x8*)&ehi[off] = hh;
        *(bf16x8*)&elo[off] = ll;
    }

    // global max|e| (wave reduce -> LDS -> thread 0)
    #pragma unroll
    for (int m = 1; m < 64; m <<= 1) me = fmaxf(me, __shfl_xor(me, m));
    if ((k & 63) == 0) wmax[k >> 6] = me;
    __syncthreads();
    if (k == 0) {
        float M = wmax[0];
        #pragma unroll
        for (int i = 1; i < 8; ++i) M = fmaxf(M, wmax[i]);
        *(float*)(ws + WS_MAXE) = M;
    }
}

// ---------------- main kernel ----------------
__global__ __launch_bounds__(256) void vq_main_kernel(
    const float* __restrict__ z, const float* __restrict__ emb,
    const char* __restrict__ ws, int* __restrict__ out)
{
    __shared__ __align__(16) unsigned short buf[2][8192];  // 2 x (ehi 4096 | elo 4096) shorts
    __shared__ __align__(16) float esqb[KCODES];

    const int t    = threadIdx.x;
    const int lane = t & 63;
    const int w    = t >> 6;
    const int g    = lane >> 4;
    const int p16  = lane & 15;

    // stage biased esq table (2KB)
    esqb[t]       = ((const float*)(ws + WS_ESQB))[t];
    esqb[t + 256] = ((const float*)(ws + WS_ESQB))[t + 256];
    const float maxe = *((const float*)(ws + WS_MAXE));

    // pixel mapping: WG covers 256 consecutive pixels, wave covers 64
    const int P0  = blockIdx.x * 256;
    const int bb  = P0 >> 12;
    const int hwW = (P0 & 4095) + w * 64;
    const float* zbase = z + (size_t)bb * (DDIM * 4096);

    // z B-fragments: 4 sets x 2 K-chunks, hi+lo splits; per-pixel partial sum|z|
    bf16x8 zh[4][2], zl[4][2];
    float  sab[4];
    #pragma unroll
    for (int s = 0; s < 4; ++s) {
        sab[s] = 0.f;
        #pragma unroll
        for (int c = 0; c < 2; ++c) {
            #pragma unroll
            for (int j = 0; j < 8; ++j) {
                int d = g * 8 + j + c * 32;
                float v = zbase[(size_t)d * 4096 + hwW + s * 16 + p16];
                sab[s] += fabsf(v);
                unsigned short h, l;
                bf16_split(v, h, l);
                zh[s][c][j] = (short)h;
                zl[s][c][j] = (short)l;
            }
        }
    }

    // double-buffered identity-copy staging: ws image -> regs -> LDS
    const float4* img = (const float4*)(ws + WS_IMG);
    float4 st0, st1, st2, st3;
#define ISSUE(P)  { int b_ = (P) * 1024 + t; st0 = img[b_]; st1 = img[b_ + 256]; \
                    st2 = img[b_ + 512]; st3 = img[b_ + 768]; }
#define WRITEB(BI){ float4* dst_ = (float4*)&buf[BI][0]; dst_[t] = st0; dst_[t + 256] = st1; \
                    dst_[t + 512] = st2; dst_[t + 768] = st3; }

    ISSUE(0);
    WRITEB(0);
    ISSUE(1);
    __syncthreads();

    // top-3 sortable keys per set: (score_bits & ~511) | code
    unsigned m1[4], m2[4], m3[4];
    #pragma unroll
    for (int s = 0; s < 4; ++s) { m1[s] = m2[s] = m3[s] = 0xFFFFFFFFu; }

    const int jj0 = g ^ (p16 & 7);
    const int jj1 = (4 + g) ^ (p16 & 7);
    const int g4  = g * 4;

    for (int pp = 0; pp < 8; ++pp) {
        const unsigned short* ehi = &buf[pp & 1][0];
        const unsigned short* elo = &buf[pp & 1][4096];

        #pragma unroll
        for (int tt = 0; tt < 4; ++tt) {
            const int row = tt * 16 + p16;
            const int ib0 = row * 64 + (jj0 << 3);
            const int ib1 = row * 64 + (jj1 << 3);
            bf16x8 ah0 = *(const bf16x8*)&ehi[ib0];
            bf16x8 ah1 = *(const bf16x8*)&ehi[ib1];
            bf16x8 al0 = *(const bf16x8*)&elo[ib0];
            bf16x8 al1 = *(const bf16x8*)&elo[ib1];
            const int ct = pp * 64 + tt * 16;
            f32x4 eq = *(const f32x4*)&esqb[ct + g4];
            const unsigned c0 = (unsigned)(ct + g4);

            #pragma unroll
            for (int s = 0; s < 4; ++s) {
                f32x4 acc = {0.f, 0.f, 0.f, 0.f};
                acc = __builtin_amdgcn_mfma_f32_16x16x32_bf16(ah0, zh[s][0], acc, 0, 0, 0);
                acc = __builtin_amdgcn_mfma_f32_16x16x32_bf16(ah1, zh[s][1], acc, 0, 0, 0);
                acc = __builtin_amdgcn_mfma_f32_16x16x32_bf16(al0, zh[s][0], acc, 0, 0, 0);
                acc = __builtin_amdgcn_mfma_f32_16x16x32_bf16(al1, zh[s][1], acc, 0, 0, 0);
                acc = __builtin_amdgcn_mfma_f32_16x16x32_bf16(ah0, zl[s][0], acc, 0, 0, 0);
                acc = __builtin_amdgcn_mfma_f32_16x16x32_bf16(ah1, zl[s][1], acc, 0, 0, 0);
                #pragma unroll
                for (int rr = 0; rr < 4; ++rr) {
                    float sc = fmaf(-2.f, acc[rr], eq[rr]);
                    unsigned key = (__float_as_uint(sc) & 0xFFFFFE00u) | (c0 + (unsigned)rr);
                    unsigned big  = umax_(key, m1[s]);
                    m1[s]         = umin_(key, m1[s]);
                    unsigned big2 = umax_(big, m2[s]);
                    m2[s]         = umin_(big, m2[s]);
                    m3[s]         = umin_(big2, m3[s]);
                }
            }
        }

        if (pp < 7) {
            WRITEB((pp + 1) & 1);
            if (pp < 6) ISSUE(pp + 2);
        }
        __syncthreads();
    }

    // merge the 4 code-partitions (lane groups) per set: butterfly xor 16, 32
    #pragma unroll
    for (int s = 0; s < 4; ++s) {
        #pragma unroll
        for (int st2 = 0; st2 < 2; ++st2) {
            const int mk = 16 << st2;
            unsigned b1 = (unsigned)__shfl_xor((int)m1[s], mk);
            unsigned b2 = (unsigned)__shfl_xor((int)m2[s], mk);
            unsigned b3 = (unsigned)__shfl_xor((int)m3[s], mk);
            float osa = __shfl_xor(sab[s], mk);
            sab[s] += osa;
            unsigned M1 = umin_(m1[s], b1), x = umax_(m1[s], b1);
            unsigned c  = umin_(m2[s], b2), d = umax_(m2[s], b2);
            unsigned M2 = umin_(x, c),      e2 = umax_(x, c);
            unsigned M3 = umin_(umin_(e2, d), umin_(m3[s], b3));
            m1[s] = M1; m2[s] = M2; m3[s] = M3;
        }
    }

    // lane owns pixel (set=g, p16): select that set's merged state
    unsigned K1 = (g == 0) ? m1[0] : (g == 1) ? m1[1] : (g == 2) ? m1[2] : m1[3];
    unsigned K2 = (g == 0) ? m2[0] : (g == 1) ? m2[1] : (g == 2) ? m2[2] : m2[3];
    unsigned K3 = (g == 0) ? m3[0] : (g == 1) ? m3[1] : (g == 2) ? m3[2] : m3[3];
    float    SA = (g == 0) ? sab[0] : (g == 1) ? sab[1] : (g == 2) ? sab[2] : sab[3];

    const float qs1 = __uint_as_float(K1 & 0xFFFFFE00u);
    const float qs2 = __uint_as_float(K2 & 0xFFFFFE00u);
    const float qs3 = __uint_as_float(K3 & 0xFFFFFE00u);
    const int   I1  = (int)(K1 & 511u);
    const int   I2  = (int)(K2 & 511u);

    // margin: 2x key quantization (6.1e-5) + np-dist ambiguity (1.7e-5) + split/MFMA err + slack
    const float MARG = 1.0e-4f + 3.0e-5f * (SA * maxe);
    const bool  f2 = (qs2 - qs1) < MARG;
    // >=3 candidates OR biased-score positivity not guaranteed -> full exact rescan
    const bool  f3 = ((qs3 - qs1) < MARG) || (2.f * SA * maxe > 0.45f) || !(qs1 > 0.f);

    const float* zrow = zbase + hwW + lane;
    const float* esqr = (const float*)(ws + WS_ESQ);
    int idx = I1;

    if (f2 && !f3) {
        // exactly two candidates: bit-exact np rescore, first-occurrence wins
        int a = min(I1, I2), b = max(I1, I2);
        float Da = np_dist_strided(zrow, emb + a * DDIM, esqr[a]);
        float Db = np_dist_strided(zrow, emb + b * DDIM, esqr[b]);
        idx = (Db < Da) ? b : a;
    }

    // rare: wave-cooperative full np rescan for flagged pixels
    unsigned long long bal = __ballot(f3);
    while (bal) {
        int pix = __ffsll((long long)bal) - 1;
        bal &= bal - 1;
        const float* zf = zbase + hwW + pix;
        float bD = 3.0e38f; int bC = 0;
        #pragma unroll
        for (int j = 0; j < 8; ++j) {
            int c = j * 64 + lane;
            float D = np_dist_strided(zf, emb + c * DDIM, esqr[c]);
            if (D < bD) { bD = D; bC = c; }
        }
        #pragma unroll
        for (int mk = 1; mk < 64; mk <<= 1) {
            float oD = __shfl_xor(bD, mk);
            int   oC = __shfl_xor(bC, mk);
            if (oD < bD || (oD == bD && oC < bC)) { bD = oD; bC = oC; }
        }
        if (lane == pix) idx = bC;
    }

    out[P0 + w * 64 + lane] = idx;
#undef ISSUE
#undef WRITEB
}

// ---------------- fallback (ws too small): round-2 verified self-contained kernel ----------------
__device__ __forceinline__ float fb_fast_score(const float4* __restrict__ e4,
                                               const float* zr, float esqk)
{
    float a0 = 0.f, a1 = 0.f, a2 = 0.f, a3 = 0.f;
    #pragma unroll
    for (int i = 0; i < DDIM / 4; ++i) {
        float4 v = e4[i];
        a0 = fmaf(zr[4*i+0], v.x, a0);
        a1 = fmaf(zr[4*i+1], v.y, a1);
        a2 = fmaf(zr[4*i+2], v.z, a2);
        a3 = fmaf(zr[4*i+3], v.w, a3);
    }
    return fmaf(-2.f, (a0 + a1) + (a2 + a3), esqk);
}

__device__ __forceinline__ float fb_np_dist(const float* __restrict__ e,
                                            const float* zr, float zsq, float esqk)
{
    float c = 0.f;
    #pragma unroll
    for (int d = 0; d < DDIM; ++d)
        c = __fadd_rn(c, __fmul_rn(zr[d], e[d]));
    return __fadd_rn(__fsub_rn(zsq, __fmul_rn(2.0f, c)), esqk);
}

__global__ __launch_bounds__(256) void vq_fallback_kernel(
    const float* __restrict__ z, const float* __restrict__ emb, int* __restrict__ out)
{
    __shared__ float esq[KCODES];
    const int t = threadIdx.x;
    for (int k = t; k < KCODES; k += 256) {
        const float* e = emb + k * DDIM;
        float r[8];
        #pragma unroll
        for (int j = 0; j < 8; ++j) r[j] = __fmul_rn(e[j], e[j]);
        #pragma unroll
        for (int i = 8; i < DDIM; i += 8)
            #pragma unroll
            for (int j = 0; j < 8; ++j)
                r[j] = __fadd_rn(r[j], __fmul_rn(e[i+j], e[i+j]));
        esq[k] = __fadd_rn(
            __fadd_rn(__fadd_rn(r[0], r[1]), __fadd_rn(r[2], r[3])),
            __fadd_rn(__fadd_rn(r[4], r[5]), __fadd_rn(r[6], r[7])));
    }
    __syncthreads();
    const int p  = blockIdx.x * 256 + t;
    const int b  = p >> 12;
    const int hw = p & 4095;
    const float* zp = z + (size_t)b * (DDIM * 4096) + hw;
    float zr[DDIM];
    #pragma unroll
    for (int d = 0; d < DDIM; ++d) zr[d] = zp[(size_t)d * 4096];
    float zsq = __fmul_rn(zr[0], zr[0]);
    #pragma unroll
    for (int d = 1; d < DDIM; ++d)
        zsq = __fadd_rn(zsq, __fmul_rn(zr[d], zr[d]));
    float m1 = 3.0e38f, m2 = 3.0e38f, m3 = 3.0e38f;
    int   i1 = 0, i2 = 0;
    for (int k = 0; k < KCODES; ++k) {
        const float s = fb_fast_score(reinterpret_cast<const float4*>(emb + k * DDIM), zr, esq[k]);
        const bool b1 = s < m1, b2 = s < m2, b3 = s < m3;
        const float nm3 = b2 ? m2 : (b3 ? s : m3);
        const float nm2 = b1 ? m1 : (b2 ? s : m2);
        const int   ni2 = b1 ? i1 : (b2 ? k : i2);
        const float nm1 = b1 ? s : m1;
        const int   ni1 = b1 ? k : i1;
        m3 = nm3; m2 = nm2; i2 = ni2; m1 = nm1; i1 = ni1;
    }
    int idx = i1;
    if (m2 - m1 < 6.0e-5f) {
        if (m3 - m1 >= 6.0e-5f) {
            const float D1 = fb_np_dist(emb + i1 * DDIM, zr, zsq, esq[i1]);
            const float D2 = fb_np_dist(emb + i2 * DDIM, zr, zsq, esq[i2]);
            const int   ka = (i1 < i2) ? i1 : i2;
            const int   kb = (i1 < i2) ? i2 : i1;
            const float Da = (i1 < i2) ? D1 : D2;
            const float Db = (i1 < i2) ? D2 : D1;
            idx = (Db < Da) ? kb : ka;
        } else {
            float bestD = 3.0e38f; int bi = 0; bool found = false;
            for (int k = 0; k < KCODES; ++k) {
                const float s = fb_fast_score(reinterpret_cast<const float4*>(emb + k * DDIM), zr, esq[k]);
                if (s < m1 + 6.0e-5f) {
                    const float Dk = fb_np_dist(emb + k * DDIM, zr, zsq, esq[k]);
                    if (!found || Dk < bestD) { bestD = Dk; bi = k; found = true; }
                }
            }
            idx = bi;
        }
    }
    out[p] = idx;
}

extern "C" void kernel_launch(void* const* d_in, const int* in_sizes, int n_in,
                              void* d_out, int out_size, void* d_ws, size_t ws_size,
                              hipStream_t stream)
{
    const float* z   = (const float*)d_in[0];
    const float* emb = (const float*)d_in[1];
    int* out = (int*)d_out;
    if (ws_size >= (size_t)WS_NEEDED) {
        hipLaunchKernelGGL(vq_pre_kernel, dim3(1), dim3(512), 0, stream, emb, (char*)d_ws);
        hipLaunchKernelGGL(vq_main_kernel, dim3(out_size / 256), dim3(256), 0, stream,
                           z, emb, (const char*)d_ws, out);
    } else {
        hipLaunchKernelGGL(vq_fallback_kernel, dim3(out_size / 256), dim3(256), 0, stream,
                           z, emb, out);
    }
}